// Round 1
// baseline (1271.949 us; speedup 1.0000x reference)
//
#include <hip/hip_runtime.h>
#include <stdint.h>

// Problem dims
#define Bdim 32
#define Pdim 256
#define Ddim 2048
#define Hdim 8192
#define Vdim 3

typedef __attribute__((ext_vector_type(8))) short short8;
typedef __attribute__((ext_vector_type(4))) float f32x4;

__device__ __forceinline__ unsigned short f2bf(float f) {
    union { float f; uint32_t u; } c; c.f = f;
    return (unsigned short)((c.u + 0x7fffu + ((c.u >> 16) & 1u)) >> 16);  // RNE
}

// ---------------- LayerNorm + affine + bf16 cast: x[8192][2048] -> xn bf16 ----------------
__global__ __launch_bounds__(256) void ln_kernel(
    const float* __restrict__ x, const int* __restrict__ idx,
    const float* __restrict__ gamma, const float* __restrict__ beta,
    unsigned short* __restrict__ xn)
{
    const int row = blockIdx.x;           // 0..B*P-1
    const int b   = row >> 8;             // /Pdim
    const int t   = threadIdx.x;
    const int v   = idx[b];

    const float4* xr = (const float4*)(x + (size_t)row * Ddim);
    float4 v0 = xr[t];
    float4 v1 = xr[t + 256];
    float s = v0.x + v0.y + v0.z + v0.w + v1.x + v1.y + v1.z + v1.w;
    float q = v0.x*v0.x + v0.y*v0.y + v0.z*v0.z + v0.w*v0.w
            + v1.x*v1.x + v1.y*v1.y + v1.z*v1.z + v1.w*v1.w;
    #pragma unroll
    for (int m = 1; m < 64; m <<= 1) {
        s += __shfl_xor(s, m);
        q += __shfl_xor(q, m);
    }
    __shared__ float red[8];
    const int w = t >> 6, lane = t & 63;
    if (lane == 0) { red[w] = s; red[4 + w] = q; }
    __syncthreads();
    s = red[0] + red[1] + red[2] + red[3];
    q = red[4] + red[5] + red[6] + red[7];
    const float mu = s * (1.0f / Ddim);
    const float rs = rsqrtf(q * (1.0f / Ddim) - mu * mu + 1e-5f);

    const float4* g4  = (const float4*)(gamma + (size_t)v * Ddim);
    const float4* bt4 = (const float4*)(beta  + (size_t)v * Ddim);
    float4 g0 = g4[t],  g1 = g4[t + 256];
    float4 e0 = bt4[t], e1 = bt4[t + 256];

    uint2 o0, o1;
    o0.x = (uint32_t)f2bf((v0.x - mu) * rs * g0.x + e0.x)
         | ((uint32_t)f2bf((v0.y - mu) * rs * g0.y + e0.y) << 16);
    o0.y = (uint32_t)f2bf((v0.z - mu) * rs * g0.z + e0.z)
         | ((uint32_t)f2bf((v0.w - mu) * rs * g0.w + e0.w) << 16);
    o1.x = (uint32_t)f2bf((v1.x - mu) * rs * g1.x + e1.x)
         | ((uint32_t)f2bf((v1.y - mu) * rs * g1.y + e1.y) << 16);
    o1.y = (uint32_t)f2bf((v1.z - mu) * rs * g1.z + e1.z)
         | ((uint32_t)f2bf((v1.w - mu) * rs * g1.w + e1.w) << 16);
    uint2* xo = (uint2*)(xn + (size_t)row * Ddim);
    xo[t] = o0;
    xo[t + 256] = o1;
}

// ---------- transpose + f32->bf16: in[z][R][C] f32 -> out[z][C][R] bf16, 64x64 tiles ----------
__global__ __launch_bounds__(256) void transpose_kernel(
    const float* __restrict__ in, unsigned short* __restrict__ out, int R, int C)
{
    __shared__ unsigned short tl[64][68];   // +4 pad: b64-aligned rows, fewer conflicts
    const size_t plane = (size_t)R * C;
    in  += (size_t)blockIdx.z * plane;
    out += (size_t)blockIdx.z * plane;
    const int r0 = blockIdx.y << 6, c0 = blockIdx.x << 6;
    const int t = threadIdx.x;
    #pragma unroll
    for (int it = 0; it < 4; ++it) {
        int lin = it * 256 + t;
        int r = lin >> 4, cq = (lin & 15) << 2;
        float4 vv = *(const float4*)(in + (size_t)(r0 + r) * C + c0 + cq);
        tl[cq + 0][r] = f2bf(vv.x);
        tl[cq + 1][r] = f2bf(vv.y);
        tl[cq + 2][r] = f2bf(vv.z);
        tl[cq + 3][r] = f2bf(vv.w);
    }
    __syncthreads();
    #pragma unroll
    for (int it = 0; it < 4; ++it) {
        int lin = it * 256 + t;
        int c = lin >> 4, rq = (lin & 15) << 2;
        ushort4 o;
        o.x = tl[c][rq + 0]; o.y = tl[c][rq + 1];
        o.z = tl[c][rq + 2]; o.w = tl[c][rq + 3];
        *(ushort4*)(out + (size_t)(c0 + c) * R + r0 + rq) = o;
    }
}

// ---------------- MFMA GEMM: C[b] = A[b] (bf16 [256][K]) x Bt[v]^T (bf16 [N][K]) ----------------
// EPI 0: C = gelu_exact(A*B + b1)  -> bf16
// EPI 1: C = A*B + b2 + xres       -> f32
#define GL16(gp, lp) __builtin_amdgcn_global_load_lds( \
    (const __attribute__((address_space(1))) void*)(gp), \
    (__attribute__((address_space(3))) void*)(lp), 16, 0, 0)

template<int K, int N, int EPI>
__global__ __launch_bounds__(256, 3) void gemm_kernel(
    const unsigned short* __restrict__ A,    // [Bdim][256][K] bf16
    const unsigned short* __restrict__ Bt,   // [Vdim][N][K]  bf16
    const float* __restrict__ bias,          // [Vdim][N]
    const int* __restrict__ idx,
    const float* __restrict__ xres,          // EPI==1: [Bdim][256][N]
    unsigned short* __restrict__ Cbf,        // EPI==0
    float* __restrict__ Cf)                  // EPI==1
{
    __shared__ short lds[8192];              // 16KB: A tile [128][32] @0, Bt tile [128][32] @4096
    const int t = threadIdx.x;
    const int lane = t & 63, w = t >> 6;
    const int wr = w >> 1, wc = w & 1;
    const int bsamp = blockIdx.z;
    const int v = idx[bsamp];
    const int n0 = blockIdx.x << 7;
    const int m0 = blockIdx.y << 7;

    const char* Ag = (const char*)(A + ((size_t)bsamp * 256 + m0) * K);
    const char* Bg = (const char*)(Bt + ((size_t)v * N + n0) * K);
    char* L = (char*)&lds[0];

    // staging geometry: linear byte o = issue*4096 + t*16 ; row=o/64 ; colbyte=o%64
    const int row_st = t >> 2;
    const int cb = (t & 3) << 4;
    const char* agp0 = Ag + (size_t)row_st * (K * 2) + cb;
    const char* agp1 = Ag + (size_t)(row_st + 64) * (K * 2) + cb;
    const char* bgp0 = Bg + (size_t)row_st * (K * 2) + cb;
    const char* bgp1 = Bg + (size_t)(row_st + 64) * (K * 2) + cb;
    char* la0 = L + (w << 10);
    char* la1 = L + 4096 + (w << 10);
    char* lb0 = L + 8192 + (w << 10);
    char* lb1 = L + 12288 + (w << 10);

    const int r15 = lane & 15, g8 = lane >> 4;
    const short* pa = lds        + (wr * 64 + r15) * 32 + g8 * 8;
    const short* pb = lds + 4096 + (wc * 64 + r15) * 32 + g8 * 8;

    f32x4 acc[4][4];
    #pragma unroll
    for (int i = 0; i < 4; ++i)
        #pragma unroll
        for (int j = 0; j < 4; ++j)
            acc[i][j] = (f32x4)(0.0f);

    for (int kt = 0; kt < K / 32; ++kt) {
        __syncthreads();                       // previous tile fully consumed
        GL16(agp0, la0);
        GL16(agp1, la1);
        GL16(bgp0, lb0);
        GL16(bgp1, lb1);
        agp0 += 64; agp1 += 64; bgp0 += 64; bgp1 += 64;
        __syncthreads();                       // vmcnt(0) drain + barrier

        short8 af[4], bf[4];
        #pragma unroll
        for (int m = 0; m < 4; ++m) af[m] = *(const short8*)(pa + m * 512);
        #pragma unroll
        for (int n = 0; n < 4; ++n) bf[n] = *(const short8*)(pb + n * 512);
        #pragma unroll
        for (int m = 0; m < 4; ++m)
            #pragma unroll
            for (int n = 0; n < 4; ++n)
                asm volatile("v_mfma_f32_16x16x32_bf16 %0, %1, %2, %0"
                             : "+v"(acc[m][n]) : "v"(af[m]), "v"(bf[n]));
    }
    asm volatile("s_nop 7\n\ts_nop 7");        // MFMA dest -> VALU read hazard slack

    // C/D layout (m89-verified): col = lane&15, row = (lane>>4)*4 + reg
    const int crow = m0 + wr * 64 + (g8 << 2);
    const int ccol = n0 + wc * 64 + r15;
    const float* bs = bias + (size_t)v * N;
    if (EPI == 0) {
        unsigned short* Co = Cbf + (size_t)bsamp * 256 * N;
        #pragma unroll
        for (int m = 0; m < 4; ++m) {
            #pragma unroll
            for (int n = 0; n < 4; ++n) {
                const int col = ccol + n * 16;
                const float bv = bs[col];
                #pragma unroll
                for (int r = 0; r < 4; ++r) {
                    const int rw = crow + m * 16 + r;
                    float val = acc[m][n][r] + bv;
                    val = 0.5f * val * (1.0f + erff(val * 0.70710678118654752f));
                    Co[(size_t)rw * N + col] = f2bf(val);
                }
            }
        }
    } else {
        float* Co = Cf + (size_t)bsamp * 256 * N;
        const float* Xr = xres + (size_t)bsamp * 256 * N;
        #pragma unroll
        for (int m = 0; m < 4; ++m) {
            #pragma unroll
            for (int n = 0; n < 4; ++n) {
                const int col = ccol + n * 16;
                const float bv = bs[col];
                #pragma unroll
                for (int r = 0; r < 4; ++r) {
                    const int rw = crow + m * 16 + r;
                    Co[(size_t)rw * N + col] = acc[m][n][r] + bv + Xr[(size_t)rw * N + col];
                }
            }
        }
    }
}

extern "C" void kernel_launch(void* const* d_in, const int* in_sizes, int n_in,
                              void* d_out, int out_size, void* d_ws, size_t ws_size,
                              hipStream_t stream) {
    const float* x     = (const float*)d_in[0];
    const int*   idx   = (const int*)d_in[1];
    const float* gamma = (const float*)d_in[2];
    const float* beta  = (const float*)d_in[3];
    const float* W1    = (const float*)d_in[4];
    const float* b1    = (const float*)d_in[5];
    const float* W2    = (const float*)d_in[6];
    const float* b2    = (const float*)d_in[7];
    float* out = (float*)d_out;

    // workspace layout (bytes): xn 32MiB | h 128MiB | W1t 96MiB | W2t 96MiB = 352MiB
    char* ws = (char*)d_ws;
    unsigned short* xn  = (unsigned short*)(ws);
    unsigned short* h   = (unsigned short*)(ws + 33554432ull);
    unsigned short* w1t = (unsigned short*)(ws + 167772160ull);
    unsigned short* w2t = (unsigned short*)(ws + 268435456ull);

    // 1) LayerNorm + bf16 cast
    ln_kernel<<<dim3(Bdim * Pdim), dim3(256), 0, stream>>>(x, idx, gamma, beta, xn);
    // 2) W1 [V][D][H] f32 -> W1t [V][H][D] bf16 ; W2 [V][H][D] f32 -> W2t [V][D][H] bf16
    transpose_kernel<<<dim3(Hdim / 64, Ddim / 64, Vdim), dim3(256), 0, stream>>>(W1, w1t, Ddim, Hdim);
    transpose_kernel<<<dim3(Ddim / 64, Hdim / 64, Vdim), dim3(256), 0, stream>>>(W2, w2t, Hdim, Ddim);
    // 3) h = gelu(xn @ W1 + b1)   [per sample: 256xK=2048 -> N=8192]
    gemm_kernel<Ddim, Hdim, 0><<<dim3(Hdim / 128, 2, Bdim), dim3(256), 0, stream>>>(
        xn, w1t, b1, idx, nullptr, h, nullptr);
    // 4) out = x + h @ W2 + b2    [per sample: 256xK=8192 -> N=2048]
    gemm_kernel<Hdim, Ddim, 1><<<dim3(Ddim / 128, 2, Bdim), dim3(256), 0, stream>>>(
        h, w2t, b2, idx, x, nullptr, out);
}